// Round 1
// baseline (2076.419 us; speedup 1.0000x reference)
//
#include <hip/hip_runtime.h>
#include <hip/hip_bf16.h>

#define N_    1024
#define L_    120
#define LROWS 122      // halo rows: row 0 and row 121 are zero; row (1+l) holds position l
#define LQ_   30
#define D_    200
#define P_    5
#define H_    230
#define R_    96
#define BAG_  8
#define B_    128
#define EMB_  610
#define CPAD_ 640
#define HT_   64

typedef __hip_bfloat16 bf16;

__device__ __forceinline__ float wred_sum64(float v) {
#pragma unroll
  for (int m = 32; m; m >>= 1) v += __shfl_xor(v, m, 64);
  return v;
}
__device__ __forceinline__ float wred_max64(float v) {
#pragma unroll
  for (int m = 32; m; m >>= 1) v = fmaxf(v, __shfl_xor(v, m, 64));
  return v;
}

// ---------------------------------------------------------------------------
// K1: per-sentence qs-attention, build x [N][LROWS][CPAD] in bf16 (halo rows 0)
// grid = N_, block = 256 (4 waves). Wave w handles rows l = w, w+4, ...
// ---------------------------------------------------------------------------
__global__ __launch_bounds__(256) void k1_attn_build_x(
    const int* __restrict__ X, const int* __restrict__ Q,
    const int* __restrict__ P1, const int* __restrict__ P2,
    const float* __restrict__ word_emb,
    const float* __restrict__ pos1_emb, const float* __restrict__ pos2_emb,
    const float* __restrict__ ws_w, const float* __restrict__ ws_b,
    const float* __restrict__ wq_w, const float* __restrict__ wq_b,
    const float* __restrict__ wsq_w, const float* __restrict__ wsq_b,
    bf16* __restrict__ xbuf)
{
  const int n = blockIdx.x;
  const int tid = threadIdx.x;
  const int wave = tid >> 6, lane = tid & 63;

  __shared__ float qs[LQ_][201];      // padded stride: conflict-free lane-j reads
  __shared__ float qdot[LQ_];
  __shared__ float wsv[D_], wqv[D_], wsqv[D_];
  __shared__ float aL[L_][LQ_];
  __shared__ float hmaxL[L_];
  __shared__ float bvecs[L_];
  __shared__ float q2s[D_];
  __shared__ float srow[4][D_];
  __shared__ float srow2[4][D_];
  __shared__ int   xidx[L_];
  __shared__ int   qidx[LQ_];
  __shared__ float red[8];

  for (int t = tid; t < D_; t += 256) { wsv[t] = ws_w[t]; wqv[t] = wq_w[t]; wsqv[t] = wsq_w[t]; }
  for (int t = tid; t < L_;  t += 256) xidx[t] = X[n * L_ + t];
  for (int t = tid; t < LQ_; t += 256) qidx[t] = Q[n * LQ_ + t];
  // zero halo rows (rows 0 and 121) every call (ws is poisoned once, never re-poisoned)
  for (int t = tid; t < 2 * CPAD_; t += 256) {
    int r = (t < CPAD_) ? 0 : (LROWS - 1);
    xbuf[((size_t)n * LROWS + r) * CPAD_ + (t % CPAD_)] = __float2bfloat16(0.f);
  }
  __syncthreads();
  for (int t = tid; t < LQ_ * D_; t += 256) {
    int j = t / D_, d = t % D_;
    qs[j][d] = word_emb[(size_t)qidx[j] * D_ + d];
  }
  __syncthreads();
  if (tid < LQ_) {
    float acc = 0.f;
    for (int d = 0; d < D_; ++d) acc += qs[tid][d] * wqv[d];
    qdot[tid] = acc + wq_b[0];
  }
  __syncthreads();

  const float wsb = ws_b[0];
  // ---- pass 1: per-row h, softmax(a), hmax ----
  for (int l = wave; l < L_; l += 4) {
    const float* sr = word_emb + (size_t)xidx[l] * D_;
    for (int d = lane; d < D_; d += 64) {
      float v = sr[d];
      srow[wave][d] = v;
      srow2[wave][d] = v * wsqv[d];
    }
    asm volatile("s_waitcnt lgkmcnt(0)" ::: "memory");
    __builtin_amdgcn_wave_barrier();
    float ps = 0.f;
    for (int d = lane; d < D_; d += 64) ps += srow[wave][d] * wsv[d];
    float sdot = wred_sum64(ps) + wsb;
    // sq dot split across 2 lanes per j (lanes 0..59 active)
    float acc = 0.f;
    if (lane < 60) {
      int j = (lane < LQ_) ? lane : lane - LQ_;
      int dbase = (lane < LQ_) ? 0 : 100;
#pragma unroll 4
      for (int d = 0; d < 100; ++d) acc += srow2[wave][dbase + d] * qs[j][dbase + d];
    }
    int src = lane + LQ_; if (src > 63) src = 63;
    float other = __shfl(acc, src, 64);
    float hj = -1e30f;
    if (lane < LQ_) hj = sdot + qdot[lane] + acc + other;
    // softmax over j within lanes 0..31
    float m = hj;
#pragma unroll
    for (int s = 16; s; s >>= 1) m = fmaxf(m, __shfl_xor(m, s, 32));
    float e = (lane < LQ_) ? expf(hj - m) : 0.f;
    float ssum = e;
#pragma unroll
    for (int s = 16; s; s >>= 1) ssum += __shfl_xor(ssum, s, 32);
    if (lane < LQ_) aL[l][lane] = e / ssum;
    if (lane == 0) hmaxL[l] = m;
  }
  __syncthreads();

  // ---- pass 2: bvec = softmax over l of hmax ----
  {
    float v = (tid < L_) ? hmaxL[tid] : -1e30f;
    float m = wred_max64(v);
    if (lane == 0) red[wave] = m;
    __syncthreads();
    m = fmaxf(fmaxf(red[0], red[1]), fmaxf(red[2], red[3]));
    float e = (tid < L_) ? expf(v - m) : 0.f;
    float s = wred_sum64(e);
    if (lane == 0) red[4 + wave] = s;
    __syncthreads();
    s = red[4] + red[5] + red[6] + red[7];
    if (tid < L_) bvecs[tid] = e / s;
  }
  __syncthreads();

  // ---- pass 3: q2s[d] = sum_l bvec[l] * s[l][d] ----
  for (int d = tid; d < D_; d += 256) {
    float acc = 0.f;
    for (int l = 0; l < L_; ++l) acc += bvecs[l] * word_emb[(size_t)xidx[l] * D_ + d];
    q2s[d] = acc;
  }
  __syncthreads();

  // ---- pass 4: build x rows ----
  for (int l = wave; l < L_; l += 4) {
    const float* sr = word_emb + (size_t)xidx[l] * D_;
    for (int d = lane; d < D_; d += 64) srow[wave][d] = sr[d];
    asm volatile("s_waitcnt lgkmcnt(0)" ::: "memory");
    __builtin_amdgcn_wave_barrier();
    bf16* xr = xbuf + ((size_t)n * LROWS + 1 + l) * CPAD_;
    for (int d = lane; d < D_; d += 64) {
      float s2q = 0.f;
#pragma unroll
      for (int j = 0; j < LQ_; ++j) s2q += aL[l][j] * qs[j][d];
      float sv = srow[wave][d];
      xr[d]          = __float2bfloat16(sv);
      xr[D_ + d]     = __float2bfloat16(sv * s2q);
      xr[2 * D_ + d] = __float2bfloat16(sv * q2s[d]);
    }
    if (lane < P_) {
      xr[3 * D_ + lane] = __float2bfloat16(pos1_emb[(size_t)P1[n * L_ + l] * P_ + lane]);
    } else if (lane < 2 * P_) {
      xr[3 * D_ + lane] = __float2bfloat16(pos2_emb[(size_t)P2[n * L_ + l] * P_ + (lane - P_)]);
    } else if (lane < 2 * P_ + (CPAD_ - EMB_)) {
      xr[EMB_ + (lane - 2 * P_)] = __float2bfloat16(0.f);
    }
  }
}

// ---------------------------------------------------------------------------
// K2: conv1d(k=3, SAME) as tiled GEMM + max-over-time + relu -> feat [N][H]
// grid = (4 h-tiles, N). block = 256. Tile: 128 pos x 64 h, per-thread 4x8.
// ---------------------------------------------------------------------------
__global__ __launch_bounds__(256) void k2_conv_feat(
    const bf16* __restrict__ xbuf, const float* __restrict__ conv_w,
    const float* __restrict__ conv_b, float* __restrict__ feat)
{
  const int n = blockIdx.y;
  const int h0 = blockIdx.x * HT_;
  const int tid = threadIdx.x;
  const int th = tid & 7;     // owns h = h0 + th*8 .. +7
  const int pg = tid >> 3;    // owns pos pg*4 .. +3

  __shared__ float As[130][33];       // As[r][cc] = x row (r-1) of this n
  __shared__ float Ws[32][3][68];     // Ws[cc][k][h']
  __shared__ float redm[32][65];

  float acc[4][8];
#pragma unroll
  for (int i = 0; i < 4; ++i)
#pragma unroll
    for (int j = 0; j < 8; ++j) acc[i][j] = 0.f;

  const size_t xbase = (size_t)n * LROWS * CPAD_;  // row 0 = halo(l=-1)

  for (int c0 = 0; c0 < CPAD_; c0 += 32) {
    for (int t = tid; t < 130 * 32; t += 256) {
      int r = t >> 5, cc = t & 31;
      // xbuf row (n*LROWS + r); r up to 129 spills into next n's rows -> only
      // feeds discarded positions (>=120); last n covered by slack rows in ws.
      As[r][cc] = __bfloat162float(xbuf[xbase + (size_t)r * CPAD_ + c0 + cc]);
    }
    for (int t = tid; t < 32 * 3 * 64; t += 256) {
      int cc = t & 31, k = (t >> 5) % 3, hp = t / 96;
      int h = h0 + hp, c = c0 + cc;
      float v = 0.f;
      if (h < H_ && c < EMB_) v = conv_w[(size_t)h * (EMB_ * 3) + c * 3 + k];
      Ws[cc][k][hp] = v;
    }
    __syncthreads();

    for (int cc = 0; cc < 32; ++cc) {
      float av[6];
#pragma unroll
      for (int i = 0; i < 6; ++i) av[i] = As[pg * 4 + i][cc];
#pragma unroll
      for (int k = 0; k < 3; ++k) {
        const float* wp = &Ws[cc][k][th * 8];
        float4 wa = *(const float4*)(wp);
        float4 wb = *(const float4*)(wp + 4);
#pragma unroll
        for (int i = 0; i < 4; ++i) {
          float a = av[i + k];
          acc[i][0] += a * wa.x; acc[i][1] += a * wa.y;
          acc[i][2] += a * wa.z; acc[i][3] += a * wa.w;
          acc[i][4] += a * wb.x; acc[i][5] += a * wb.y;
          acc[i][6] += a * wb.z; acc[i][7] += a * wb.w;
        }
      }
    }
    __syncthreads();
  }

  // max over valid positions
#pragma unroll
  for (int j = 0; j < 8; ++j) {
    float m = -1e30f;
#pragma unroll
    for (int i = 0; i < 4; ++i)
      if (pg * 4 + i < L_) m = fmaxf(m, acc[i][j]);
    redm[pg][th * 8 + j] = m;
  }
  __syncthreads();
  if (tid < HT_) {
    float m = -1e30f;
    for (int g = 0; g < 32; ++g) m = fmaxf(m, redm[g][tid]);
    int h = h0 + tid;
    if (h < H_) feat[(size_t)n * H_ + h] = fmaxf(0.f, m + conv_b[h]);
  }
}

// ---------------------------------------------------------------------------
// K3: bag self-attention + selective attention + final projection -> out [B][R]
// grid = B_, block = 256. Bags are uniform (X_Scope = [b*8, b*8+8)).
// ---------------------------------------------------------------------------
__global__ __launch_bounds__(256) void k3_bag(
    const float* __restrict__ feat, const int* __restrict__ X_Rel,
    const float* __restrict__ rel_w, const float* __restrict__ rel_b,
    float* __restrict__ out)
{
  const int b = blockIdx.x;
  const int tid = threadIdx.x;
  __shared__ float f[BAG_][231];
  __shared__ float f2[BAG_][231];
  __shared__ float sc[BAG_][BAG_];
  __shared__ float relq[H_];
  __shared__ float zred[BAG_];
  __shared__ float wsel[BAG_];
  __shared__ float brep[H_];

  for (int t = tid; t < BAG_ * H_; t += 256) {
    int i = t / H_, h = t % H_;
    f[i][h] = feat[(size_t)(b * BAG_ + i) * H_ + h];
  }
  const int rel = X_Rel[b];
  for (int t = tid; t < H_; t += 256) relq[t] = rel_w[(size_t)rel * H_ + t];
  __syncthreads();

  if (tid < BAG_ * BAG_) {
    int i = tid >> 3, j = tid & 7;
    float acc = 0.f;
    for (int h = 0; h < H_; ++h) acc += f[i][h] * f[j][h];
    sc[i][j] = acc * (1.0f / sqrtf((float)H_));
  }
  __syncthreads();
  if (tid < BAG_) {
    float m = -1e30f;
    for (int j = 0; j < BAG_; ++j) m = fmaxf(m, sc[tid][j]);
    float s = 0.f;
    for (int j = 0; j < BAG_; ++j) { float e = expf(sc[tid][j] - m); sc[tid][j] = e; s += e; }
    float inv = 1.0f / s;
    for (int j = 0; j < BAG_; ++j) sc[tid][j] *= inv;
  }
  __syncthreads();
  for (int t = tid; t < BAG_ * H_; t += 256) {
    int i = t / H_, h = t % H_;
    float acc = 0.f;
#pragma unroll
    for (int j = 0; j < BAG_; ++j) acc += sc[i][j] * f[j][h];
    f2[i][h] = acc;
  }
  __syncthreads();
  if (tid < BAG_) {
    float acc = 0.f;
    for (int h = 0; h < H_; ++h) acc += f2[tid][h] * relq[h];
    zred[tid] = acc;
  }
  __syncthreads();
  if (tid == 0) {
    float m = -1e30f;
    for (int i = 0; i < BAG_; ++i) m = fmaxf(m, zred[i]);
    float s = 0.f;
    for (int i = 0; i < BAG_; ++i) { float e = expf(zred[i] - m); wsel[i] = e; s += e; }
    float inv = 1.0f / s;
    for (int i = 0; i < BAG_; ++i) wsel[i] *= inv;
  }
  __syncthreads();
  for (int t = tid; t < H_; t += 256) {
    float acc = 0.f;
#pragma unroll
    for (int i = 0; i < BAG_; ++i) acc += wsel[i] * f2[i][t];
    brep[t] = acc;
  }
  __syncthreads();
  if (tid < R_) {
    float acc = 0.f;
    for (int h = 0; h < H_; ++h) acc += brep[h] * rel_w[(size_t)tid * H_ + h];
    out[(size_t)b * R_ + tid] = acc + rel_b[tid];
  }
}

// ---------------------------------------------------------------------------
extern "C" void kernel_launch(void* const* d_in, const int* in_sizes, int n_in,
                              void* d_out, int out_size, void* d_ws, size_t ws_size,
                              hipStream_t stream)
{
  const int*   X        = (const int*)d_in[0];
  const int*   Q        = (const int*)d_in[1];
  const int*   P1       = (const int*)d_in[2];
  const int*   P2       = (const int*)d_in[3];
  // d_in[4] = X_Scope (uniform bags of 8; bag_id = i/8)
  const int*   X_Rel    = (const int*)d_in[5];
  const float* word_emb = (const float*)d_in[6];
  const float* pos1_emb = (const float*)d_in[7];
  const float* pos2_emb = (const float*)d_in[8];
  const float* ws_w     = (const float*)d_in[9];
  const float* ws_b     = (const float*)d_in[10];
  const float* wq_w     = (const float*)d_in[11];
  const float* wq_b     = (const float*)d_in[12];
  const float* wsq_w    = (const float*)d_in[13];
  const float* wsq_b    = (const float*)d_in[14];
  const float* conv_w   = (const float*)d_in[15];
  const float* conv_b   = (const float*)d_in[16];
  const float* rel_w    = (const float*)d_in[17];
  const float* rel_b    = (const float*)d_in[18];

  // ws layout: xbuf bf16 [N][LROWS][CPAD] (+8 slack rows), then feat f32 [N][H]
  const size_t xbuf_rows  = (size_t)N_ * LROWS + 8;
  const size_t xbuf_bytes = xbuf_rows * CPAD_ * sizeof(bf16);
  bf16*  xbuf = (bf16*)d_ws;
  float* feat = (float*)((char*)d_ws + ((xbuf_bytes + 255) & ~(size_t)255));

  k1_attn_build_x<<<N_, 256, 0, stream>>>(X, Q, P1, P2, word_emb, pos1_emb, pos2_emb,
                                          ws_w, ws_b, wq_w, wq_b, wsq_w, wsq_b, xbuf);
  k2_conv_feat<<<dim3(4, N_), 256, 0, stream>>>(xbuf, conv_w, conv_b, feat);
  k3_bag<<<B_, 256, 0, stream>>>(feat, X_Rel, rel_w, rel_b, (float*)d_out);
}

// Round 2
// 559.649 us; speedup vs baseline: 3.7102x; 3.7102x over previous
//
#include <hip/hip_runtime.h>
#include <hip/hip_bf16.h>

#define N_    1024
#define L_    120
#define LROWS 122      // halo rows: row 0 and row 121 are zero; row (1+l) holds position l
#define LQ_   30
#define D_    200
#define P_    5
#define H_    230
#define R_    96
#define BAG_  8
#define B_    128
#define EMB_  610
#define CPAD_ 640
#define NT_   256      // h tile (padded 230->256)
#define MT_   128      // pos tile (120->128)

typedef __hip_bfloat16 bf16;
typedef __attribute__((ext_vector_type(8))) short short8;
typedef __attribute__((ext_vector_type(4))) float f32x4;

__device__ __forceinline__ float wred_sum64(float v) {
#pragma unroll
  for (int m = 32; m; m >>= 1) v += __shfl_xor(v, m, 64);
  return v;
}
__device__ __forceinline__ float wred_max64(float v) {
#pragma unroll
  for (int m = 32; m; m >>= 1) v = fmaxf(v, __shfl_xor(v, m, 64));
  return v;
}

// ---------------------------------------------------------------------------
// K0: repack conv_w f32 [H][EMB][3] -> bf16 fragment-ready wt[k][cb][ni][lane][8]
//     (B^T frag layout: h = ni*16 + (lane&15), c = cb*32 + (lane>>4)*8 + e)
//     Also zero the 8 slack rows after the last n's halo.
// ---------------------------------------------------------------------------
__global__ __launch_bounds__(256) void k0_prep_w(
    const float* __restrict__ conv_w, bf16* __restrict__ wt, bf16* __restrict__ xbuf)
{
  const int idx = blockIdx.x * 256 + threadIdx.x;
  if (idx < 3 * 20 * 16 * 64 * 8) {
    int e = idx & 7, lane = (idx >> 3) & 63;
    int fid = idx >> 9;                 // 0..959
    int ni = fid & 15, cb = (fid >> 4) % 20, k = fid / 320;
    int h = ni * 16 + (lane & 15);
    int c = cb * 32 + ((lane >> 4) << 3) + e;
    float v = (h < H_ && c < EMB_) ? conv_w[(size_t)h * (EMB_ * 3) + c * 3 + k] : 0.f;
    wt[idx] = __float2bfloat16(v);
  }
  if (idx < 8 * CPAD_) {
    xbuf[(size_t)N_ * LROWS * CPAD_ + idx] = __float2bfloat16(0.f);
  }
}

// ---------------------------------------------------------------------------
// K1: per-sentence qs-attention, build x [N][LROWS][CPAD] in bf16 (halo rows 0)
// grid = N_, block = 256 (4 waves). Wave w handles rows l = w, w+4, ...
// ---------------------------------------------------------------------------
__global__ __launch_bounds__(256) void k1_attn_build_x(
    const int* __restrict__ X, const int* __restrict__ Q,
    const int* __restrict__ P1, const int* __restrict__ P2,
    const float* __restrict__ word_emb,
    const float* __restrict__ pos1_emb, const float* __restrict__ pos2_emb,
    const float* __restrict__ ws_w, const float* __restrict__ ws_b,
    const float* __restrict__ wq_w, const float* __restrict__ wq_b,
    const float* __restrict__ wsq_w, const float* __restrict__ wsq_b,
    bf16* __restrict__ xbuf)
{
  const int n = blockIdx.x;
  const int tid = threadIdx.x;
  const int wave = tid >> 6, lane = tid & 63;

  __shared__ float qs[LQ_][201];
  __shared__ float qdot[LQ_];
  __shared__ float wsv[D_], wqv[D_], wsqv[D_];
  __shared__ float aL[L_][LQ_];
  __shared__ float hmaxL[L_];
  __shared__ float bvecs[L_];
  __shared__ float q2s[D_];
  __shared__ float srow[4][D_];
  __shared__ float srow2[4][D_];
  __shared__ int   xidx[L_];
  __shared__ int   qidx[LQ_];
  __shared__ float red[8];

  for (int t = tid; t < D_; t += 256) { wsv[t] = ws_w[t]; wqv[t] = wq_w[t]; wsqv[t] = wsq_w[t]; }
  for (int t = tid; t < L_;  t += 256) xidx[t] = X[n * L_ + t];
  for (int t = tid; t < LQ_; t += 256) qidx[t] = Q[n * LQ_ + t];
  for (int t = tid; t < 2 * CPAD_; t += 256) {
    int r = (t < CPAD_) ? 0 : (LROWS - 1);
    xbuf[((size_t)n * LROWS + r) * CPAD_ + (t % CPAD_)] = __float2bfloat16(0.f);
  }
  __syncthreads();
  for (int t = tid; t < LQ_ * D_; t += 256) {
    int j = t / D_, d = t % D_;
    qs[j][d] = word_emb[(size_t)qidx[j] * D_ + d];
  }
  __syncthreads();
  if (tid < LQ_) {
    float acc = 0.f;
    for (int d = 0; d < D_; ++d) acc += qs[tid][d] * wqv[d];
    qdot[tid] = acc + wq_b[0];
  }
  __syncthreads();

  const float wsb = ws_b[0];
  for (int l = wave; l < L_; l += 4) {
    const float* sr = word_emb + (size_t)xidx[l] * D_;
    for (int d = lane; d < D_; d += 64) {
      float v = sr[d];
      srow[wave][d] = v;
      srow2[wave][d] = v * wsqv[d];
    }
    asm volatile("s_waitcnt lgkmcnt(0)" ::: "memory");
    __builtin_amdgcn_wave_barrier();
    float ps = 0.f;
    for (int d = lane; d < D_; d += 64) ps += srow[wave][d] * wsv[d];
    float sdot = wred_sum64(ps) + wsb;
    float acc = 0.f;
    if (lane < 60) {
      int j = (lane < LQ_) ? lane : lane - LQ_;
      int dbase = (lane < LQ_) ? 0 : 100;
#pragma unroll 4
      for (int d = 0; d < 100; ++d) acc += srow2[wave][dbase + d] * qs[j][dbase + d];
    }
    int src = lane + LQ_; if (src > 63) src = 63;
    float other = __shfl(acc, src, 64);
    float hj = -1e30f;
    if (lane < LQ_) hj = sdot + qdot[lane] + acc + other;
    float m = hj;
#pragma unroll
    for (int s = 16; s; s >>= 1) m = fmaxf(m, __shfl_xor(m, s, 32));
    float e = (lane < LQ_) ? expf(hj - m) : 0.f;
    float ssum = e;
#pragma unroll
    for (int s = 16; s; s >>= 1) ssum += __shfl_xor(ssum, s, 32);
    if (lane < LQ_) aL[l][lane] = e / ssum;
    if (lane == 0) hmaxL[l] = m;
  }
  __syncthreads();

  {
    float v = (tid < L_) ? hmaxL[tid] : -1e30f;
    float m = wred_max64(v);
    if (lane == 0) red[wave] = m;
    __syncthreads();
    m = fmaxf(fmaxf(red[0], red[1]), fmaxf(red[2], red[3]));
    float e = (tid < L_) ? expf(v - m) : 0.f;
    float s = wred_sum64(e);
    if (lane == 0) red[4 + wave] = s;
    __syncthreads();
    s = red[4] + red[5] + red[6] + red[7];
    if (tid < L_) bvecs[tid] = e / s;
  }
  __syncthreads();

  for (int d = tid; d < D_; d += 256) {
    float acc = 0.f;
    for (int l = 0; l < L_; ++l) acc += bvecs[l] * word_emb[(size_t)xidx[l] * D_ + d];
    q2s[d] = acc;
  }
  __syncthreads();

  for (int l = wave; l < L_; l += 4) {
    const float* sr = word_emb + (size_t)xidx[l] * D_;
    for (int d = lane; d < D_; d += 64) srow[wave][d] = sr[d];
    asm volatile("s_waitcnt lgkmcnt(0)" ::: "memory");
    __builtin_amdgcn_wave_barrier();
    bf16* xr = xbuf + ((size_t)n * LROWS + 1 + l) * CPAD_;
    for (int d = lane; d < D_; d += 64) {
      float s2q = 0.f;
#pragma unroll
      for (int j = 0; j < LQ_; ++j) s2q += aL[l][j] * qs[j][d];
      float sv = srow[wave][d];
      xr[d]          = __float2bfloat16(sv);
      xr[D_ + d]     = __float2bfloat16(sv * s2q);
      xr[2 * D_ + d] = __float2bfloat16(sv * q2s[d]);
    }
    if (lane < P_) {
      xr[3 * D_ + lane] = __float2bfloat16(pos1_emb[(size_t)P1[n * L_ + l] * P_ + lane]);
    } else if (lane < 2 * P_) {
      xr[3 * D_ + lane] = __float2bfloat16(pos2_emb[(size_t)P2[n * L_ + l] * P_ + (lane - P_)]);
    } else if (lane < 2 * P_ + (CPAD_ - EMB_)) {
      xr[EMB_ + (lane - 2 * P_)] = __float2bfloat16(0.f);
    }
  }
}

// ---------------------------------------------------------------------------
// K2: conv1d(k=3,SAME) as MFMA bf16 GEMM + max-over-time + relu -> feat [N][H]
// grid = N_, block = 512 (8 waves, 2M x 4N). Per-block tile: M=128 pos, N=256 h.
// K = 3 shifts x 640 chans; A staged in LDS [130][40] per 32-chan step,
// B frags read coalesced from frag-ready wt (L2-hot, 983 KB).
// ---------------------------------------------------------------------------
__global__ __launch_bounds__(512) void k2_conv_mfma(
    const bf16* __restrict__ xbuf, const bf16* __restrict__ wt,
    const float* __restrict__ conv_b, float* __restrict__ feat)
{
  const int n = blockIdx.x;
  const int tid = threadIdx.x;
  const int wave = tid >> 6, lane = tid & 63;
  const int wm = wave >> 2, wn = wave & 3;

  __shared__ short At[130][40];       // rows -1..128 (halo coords), pad-40 stride
  __shared__ float hred[8][64];

  f32x4 acc[4][4];
#pragma unroll
  for (int i = 0; i < 4; ++i)
#pragma unroll
    for (int j = 0; j < 4; ++j) acc[i][j] = (f32x4){0.f, 0.f, 0.f, 0.f};

  const short* xs = (const short*)xbuf;
  const short* wts = (const short*)wt;
  const size_t xbase = (size_t)n * LROWS * CPAD_;
  const int arow = (lane & 15), agrp = (lane >> 4) << 3;

  for (int c0 = 0; c0 < CPAD_; c0 += 32) {
    __syncthreads();
    for (int t = tid; t < 520; t += 512) {
      int r = t >> 2, cc = (t & 3) * 8;
      *(short8*)&At[r][cc] = *(const short8*)(xs + xbase + (size_t)r * CPAD_ + c0 + cc);
    }
    __syncthreads();
#pragma unroll
    for (int k = 0; k < 3; ++k) {
      short8 af[4];
#pragma unroll
      for (int mi = 0; mi < 4; ++mi)
        af[mi] = *(const short8*)&At[wm * 64 + mi * 16 + arow + k][agrp];
#pragma unroll
      for (int ni = 0; ni < 4; ++ni) {
        const short8 bf = *(const short8*)(
            wts + (((size_t)((k * 20 + (c0 >> 5)) * 16 + wn * 4 + ni)) << 9) + lane * 8);
#pragma unroll
        for (int mi = 0; mi < 4; ++mi)
          acc[mi][ni] = __builtin_amdgcn_mfma_f32_16x16x32_bf16(af[mi], bf, acc[mi][ni], 0, 0, 0);
      }
    }
  }

  // epilogue: max over valid pos, cross-lane reduce, relu(+bias)
  const int pbase = wm * 64 + ((lane >> 4) << 2);
#pragma unroll
  for (int ni = 0; ni < 4; ++ni) {
    float m = -1e30f;
#pragma unroll
    for (int mi = 0; mi < 4; ++mi) {
#pragma unroll
      for (int reg = 0; reg < 4; ++reg) {
        int pos = pbase + mi * 16 + reg;
        if (pos < L_) m = fmaxf(m, acc[mi][ni][reg]);
      }
    }
    m = fmaxf(m, __shfl_xor(m, 16, 64));
    m = fmaxf(m, __shfl_xor(m, 32, 64));
    if ((lane >> 4) == 0) hred[wave][ni * 16 + (lane & 15)] = m;
  }
  __syncthreads();
  for (int h = tid; h < H_; h += 512) {
    int wn2 = h >> 6, hl = h & 63;
    float m = fmaxf(hred[wn2][hl], hred[wn2 + 4][hl]);
    feat[(size_t)n * H_ + h] = fmaxf(0.f, m + conv_b[h]);
  }
}

// ---------------------------------------------------------------------------
// K3: bag self-attention + selective attention + final projection -> out [B][R]
// ---------------------------------------------------------------------------
__global__ __launch_bounds__(256) void k3_bag(
    const float* __restrict__ feat, const int* __restrict__ X_Rel,
    const float* __restrict__ rel_w, const float* __restrict__ rel_b,
    float* __restrict__ out)
{
  const int b = blockIdx.x;
  const int tid = threadIdx.x;
  __shared__ float f[BAG_][231];
  __shared__ float f2[BAG_][231];
  __shared__ float sc[BAG_][BAG_];
  __shared__ float relq[H_];
  __shared__ float zred[BAG_];
  __shared__ float wsel[BAG_];
  __shared__ float brep[H_];

  for (int t = tid; t < BAG_ * H_; t += 256) {
    int i = t / H_, h = t % H_;
    f[i][h] = feat[(size_t)(b * BAG_ + i) * H_ + h];
  }
  const int rel = X_Rel[b];
  for (int t = tid; t < H_; t += 256) relq[t] = rel_w[(size_t)rel * H_ + t];
  __syncthreads();

  if (tid < BAG_ * BAG_) {
    int i = tid >> 3, j = tid & 7;
    float acc = 0.f;
    for (int h = 0; h < H_; ++h) acc += f[i][h] * f[j][h];
    sc[i][j] = acc * (1.0f / sqrtf((float)H_));
  }
  __syncthreads();
  if (tid < BAG_) {
    float m = -1e30f;
    for (int j = 0; j < BAG_; ++j) m = fmaxf(m, sc[tid][j]);
    float s = 0.f;
    for (int j = 0; j < BAG_; ++j) { float e = expf(sc[tid][j] - m); sc[tid][j] = e; s += e; }
    float inv = 1.0f / s;
    for (int j = 0; j < BAG_; ++j) sc[tid][j] *= inv;
  }
  __syncthreads();
  for (int t = tid; t < BAG_ * H_; t += 256) {
    int i = t / H_, h = t % H_;
    float acc = 0.f;
#pragma unroll
    for (int j = 0; j < BAG_; ++j) acc += sc[i][j] * f[j][h];
    f2[i][h] = acc;
  }
  __syncthreads();
  if (tid < BAG_) {
    float acc = 0.f;
    for (int h = 0; h < H_; ++h) acc += f2[tid][h] * relq[h];
    zred[tid] = acc;
  }
  __syncthreads();
  if (tid == 0) {
    float m = -1e30f;
    for (int i = 0; i < BAG_; ++i) m = fmaxf(m, zred[i]);
    float s = 0.f;
    for (int i = 0; i < BAG_; ++i) { float e = expf(zred[i] - m); wsel[i] = e; s += e; }
    float inv = 1.0f / s;
    for (int i = 0; i < BAG_; ++i) wsel[i] *= inv;
  }
  __syncthreads();
  for (int t = tid; t < H_; t += 256) {
    float acc = 0.f;
#pragma unroll
    for (int i = 0; i < BAG_; ++i) acc += wsel[i] * f2[i][t];
    brep[t] = acc;
  }
  __syncthreads();
  if (tid < R_) {
    float acc = 0.f;
    for (int h = 0; h < H_; ++h) acc += brep[h] * rel_w[(size_t)tid * H_ + h];
    out[(size_t)b * R_ + tid] = acc + rel_b[tid];
  }
}

// ---------------------------------------------------------------------------
extern "C" void kernel_launch(void* const* d_in, const int* in_sizes, int n_in,
                              void* d_out, int out_size, void* d_ws, size_t ws_size,
                              hipStream_t stream)
{
  const int*   X        = (const int*)d_in[0];
  const int*   Q        = (const int*)d_in[1];
  const int*   P1       = (const int*)d_in[2];
  const int*   P2       = (const int*)d_in[3];
  // d_in[4] = X_Scope (uniform bags of 8; bag_id = i/8)
  const int*   X_Rel    = (const int*)d_in[5];
  const float* word_emb = (const float*)d_in[6];
  const float* pos1_emb = (const float*)d_in[7];
  const float* pos2_emb = (const float*)d_in[8];
  const float* ws_w     = (const float*)d_in[9];
  const float* ws_b     = (const float*)d_in[10];
  const float* wq_w     = (const float*)d_in[11];
  const float* wq_b     = (const float*)d_in[12];
  const float* wsq_w    = (const float*)d_in[13];
  const float* wsq_b    = (const float*)d_in[14];
  const float* conv_w   = (const float*)d_in[15];
  const float* conv_b   = (const float*)d_in[16];
  const float* rel_w    = (const float*)d_in[17];
  const float* rel_b    = (const float*)d_in[18];

  // ws layout: xbuf bf16 [N][LROWS][CPAD] (+8 slack rows) | feat f32 [N][H] | wt bf16 frags
  const size_t xbuf_rows  = (size_t)N_ * LROWS + 8;
  const size_t xbuf_bytes = (xbuf_rows * CPAD_ * sizeof(bf16) + 255) & ~(size_t)255;
  const size_t feat_bytes = ((size_t)N_ * H_ * sizeof(float) + 255) & ~(size_t)255;
  bf16*  xbuf = (bf16*)d_ws;
  float* feat = (float*)((char*)d_ws + xbuf_bytes);
  bf16*  wt   = (bf16*)((char*)d_ws + xbuf_bytes + feat_bytes);

  k0_prep_w<<<1920, 256, 0, stream>>>(conv_w, wt, xbuf);
  k1_attn_build_x<<<N_, 256, 0, stream>>>(X, Q, P1, P2, word_emb, pos1_emb, pos2_emb,
                                          ws_w, ws_b, wq_w, wq_b, wsq_w, wsq_b, xbuf);
  k2_conv_mfma<<<N_, 512, 0, stream>>>(xbuf, wt, conv_b, feat);
  k3_bag<<<B_, 256, 0, stream>>>(feat, X_Rel, rel_w, rel_b, (float*)d_out);
}

// Round 3
// 280.790 us; speedup vs baseline: 7.3949x; 1.9931x over previous
//
#include <hip/hip_runtime.h>
#include <hip/hip_bf16.h>

#define N_    1024
#define L_    120
#define LROWS 122      // halo rows: row 0 and row 121 are zero; row (1+l) holds position l
#define LQ_   30
#define D_    200
#define P_    5
#define H_    230
#define R_    96
#define BAG_  8
#define B_    128
#define EMB_  610
#define CPAD_ 640

typedef __hip_bfloat16 bf16;
typedef __attribute__((ext_vector_type(8))) short short8;
typedef __attribute__((ext_vector_type(4))) short short4_;
typedef __attribute__((ext_vector_type(4))) float f32x4;

__device__ __forceinline__ float wred_sum64(float v) {
#pragma unroll
  for (int m = 32; m; m >>= 1) v += __shfl_xor(v, m, 64);
  return v;
}
__device__ __forceinline__ float wred_max64(float v) {
#pragma unroll
  for (int m = 32; m; m >>= 1) v = fmaxf(v, __shfl_xor(v, m, 64));
  return v;
}
__device__ __forceinline__ short f2b(float f) {
  bf16 h = __float2bfloat16(f);
  return __builtin_bit_cast(short, h);
}

// ---------------------------------------------------------------------------
// K0: repack conv_w f32 [H][EMB][3] -> bf16 fragment-ready wt[k][cb][ni][lane][8]
//     (B^T frag layout: h = ni*16 + (lane&15), c = cb*32 + (lane>>4)*8 + e)
//     Also zero the 8 slack rows after the last n's halo.
// ---------------------------------------------------------------------------
__global__ __launch_bounds__(256) void k0_prep_w(
    const float* __restrict__ conv_w, bf16* __restrict__ wt, bf16* __restrict__ xbuf)
{
  const int idx = blockIdx.x * 256 + threadIdx.x;
  if (idx < 3 * 20 * 16 * 64 * 8) {
    int e = idx & 7, lane = (idx >> 3) & 63;
    int fid = idx >> 9;                 // 0..959
    int ni = fid & 15, cb = (fid >> 4) % 20, k = fid / 320;
    int h = ni * 16 + (lane & 15);
    int c = cb * 32 + ((lane >> 4) << 3) + e;
    float v = (h < H_ && c < EMB_) ? conv_w[(size_t)h * (EMB_ * 3) + c * 3 + k] : 0.f;
    wt[idx] = __float2bfloat16(v);
  }
  if (idx < 8 * CPAD_) {
    xbuf[(size_t)N_ * LROWS * CPAD_ + idx] = __float2bfloat16(0.f);
  }
}

// ---------------------------------------------------------------------------
// K1 (MFMA attention): per-sentence qs-attention, build x [N][LROWS][CPAD] bf16.
// grid = N_, block = 512 (8 waves).
//  phase A: stage s -> xbuf cols [0,200) (bf16) + sdot; stage q -> qsw (q*wsq),
//           qT (transposed), qdot; halo rows + pos cols + pad cols.
//  phase B: GEMM1  h = s @ qsw^T  (M=128, N=32, K=224) via mfma_16x16x32;
//           A-frags read from just-written global xbuf (L1/L2-hot);
//           row-softmax fully lane-parallel -> a_bf (A-frag layout), hmax.
//  phase C: bvec = softmax_l(hmax)  (wave 0); q2s = bvec @ s.
//  phase D: GEMM2  s2q = a @ qT (M=128, N=208, K=32), fused epilogue writes
//           x[:,200+d] = s*s2q and x[:,400+d] = s*q2s.
// K-padding note: GEMM1 A reads xbuf cols [200,224) = stale x2 data (finite:
// 0xAA poison = tiny bf16, or previous replay's identical values) times
// zeroed qsw rows -> contributes exactly 0; deterministic.
// ---------------------------------------------------------------------------
__global__ __launch_bounds__(512) void k1_attn_build_x(
    const int* __restrict__ X, const int* __restrict__ Q,
    const int* __restrict__ P1, const int* __restrict__ P2,
    const float* __restrict__ word_emb,
    const float* __restrict__ pos1_emb, const float* __restrict__ pos2_emb,
    const float* __restrict__ ws_w, const float* __restrict__ ws_b,
    const float* __restrict__ wq_w, const float* __restrict__ wq_b,
    const float* __restrict__ wsq_w, const float* __restrict__ wsq_b,
    bf16* xbuf)
{
  const int n = blockIdx.x;
  const int tid = threadIdx.x;
  const int w = tid >> 6, lane = tid & 63;
  const int g = lane >> 4, c = lane & 15;

  // strides chosen for 16B alignment + <=2-way bank aliasing on frag reads:
  // 232 shorts = 464B = 116 dw, 116%32=20 (8 distinct banks over 16 rows)
  // 40 shorts = 80B = 20 dw, 20%32=20 (8 distinct banks over 16 rows)
  __shared__ bf16  qsw[32][232];      // (q * wsq)[j][k], zero-padded
  __shared__ bf16  qT[208][40];       // q^T: [d][j], zero-padded
  __shared__ bf16  a_bf[128][40];     // softmax attn weights, A-frag layout
  __shared__ float wsv[D_], wqv[D_], wsqv[D_];
  __shared__ float sdot[128], qdot[32], hmax[128], bvec[L_];
  __shared__ float q2p[2][D_];

  // ---- init ----
  for (int t = tid; t < 32 * 232 / 2; t += 512) ((int*)qsw)[t] = 0;
  for (int t = tid; t < 208 * 40 / 2; t += 512) ((int*)qT)[t] = 0;
  if (tid < 2) qdot[30 + tid] = 0.f;
  if (tid >= 120 && tid < 128) sdot[tid] = 0.f;    // keep junk rows finite
  for (int t = tid; t < D_; t += 512) { wsv[t] = ws_w[t]; wqv[t] = wq_w[t]; wsqv[t] = wsq_w[t]; }
  __syncthreads();

  const float wsb = ws_b[0], wqb = wq_b[0];
  bf16* xrow_base = xbuf + (size_t)n * LROWS * CPAD_;

  // ---- phase A: staging ----
  for (int l = w; l < L_; l += 8) {
    const int idx = X[n * L_ + l];
    bf16* xr = xrow_base + (size_t)(1 + l) * CPAD_;
    float part = 0.f;
    if (lane < 50) {
      const int d = lane * 4;
      float4 v = *(const float4*)(word_emb + (size_t)idx * D_ + d);
      part = v.x * wsv[d] + v.y * wsv[d + 1] + v.z * wsv[d + 2] + v.w * wsv[d + 3];
      short4_ pk;
      pk.x = f2b(v.x); pk.y = f2b(v.y); pk.z = f2b(v.z); pk.w = f2b(v.w);
      *(short4_*)(xr + d) = pk;
    } else {
      int p = lane - 50;
      if (p < P_) {
        xr[3 * D_ + p] = __float2bfloat16(pos1_emb[(size_t)P1[n * L_ + l] * P_ + p]);
      } else if (p < 2 * P_) {
        xr[3 * D_ + p] = __float2bfloat16(pos2_emb[(size_t)P2[n * L_ + l] * P_ + (p - P_)]);
      }
    }
    float sum = wred_sum64(part);
    if (lane == 0) sdot[l] = sum + wsb;
  }
  for (int j = w; j < LQ_; j += 8) {
    const int idx = Q[n * LQ_ + j];
    float part = 0.f;
    if (lane < 50) {
      const int d = lane * 4;
      float4 v = *(const float4*)(word_emb + (size_t)idx * D_ + d);
      part = v.x * wqv[d] + v.y * wqv[d + 1] + v.z * wqv[d + 2] + v.w * wqv[d + 3];
      short4_ pk;
      pk.x = f2b(v.x * wsqv[d]);     pk.y = f2b(v.y * wsqv[d + 1]);
      pk.z = f2b(v.z * wsqv[d + 2]); pk.w = f2b(v.w * wsqv[d + 3]);
      *(short4_*)(&qsw[j][d]) = pk;
      qT[d][j]     = __float2bfloat16(v.x);
      qT[d + 1][j] = __float2bfloat16(v.y);
      qT[d + 2][j] = __float2bfloat16(v.z);
      qT[d + 3][j] = __float2bfloat16(v.w);
    }
    float sum = wred_sum64(part);
    if (lane == 0) qdot[j] = sum + wqb;
  }
  // halo rows 0 and 121
  for (int t = tid; t < 2 * CPAD_; t += 512) {
    int r = (t < CPAD_) ? 0 : (LROWS - 1);
    xrow_base[(size_t)r * CPAD_ + (t & (CPAD_ - 1))] = __float2bfloat16(0.f);
  }
  // pad cols [610, 640)
  for (int t = tid; t < L_ * 30; t += 512) {
    int l = t / 30, cc = EMB_ + t % 30;
    xrow_base[(size_t)(1 + l) * CPAD_ + cc] = __float2bfloat16(0.f);
  }
  __syncthreads();

  // ---- phase B: GEMM1 + softmax ----
  f32x4 acc0 = {0.f, 0.f, 0.f, 0.f}, acc1 = {0.f, 0.f, 0.f, 0.f};
  {
    const short* xs = (const short*)xbuf;
    const size_t abase = ((size_t)n * LROWS + 1 + 16 * w + c) * CPAD_ + g * 8;
#pragma unroll
    for (int kk = 0; kk < 7; ++kk) {
      short8 af = *(const short8*)(xs + abase + kk * 32);
      short8 b0 = *(const short8*)&qsw[c][kk * 32 + g * 8];
      short8 b1 = *(const short8*)&qsw[16 + c][kk * 32 + g * 8];
      acc0 = __builtin_amdgcn_mfma_f32_16x16x32_bf16(af, b0, acc0, 0, 0, 0);
      acc1 = __builtin_amdgcn_mfma_f32_16x16x32_bf16(af, b1, acc1, 0, 0, 0);
    }
  }
  {
    const int rbase = 16 * w + 4 * g;
    const float qd0 = qdot[c], qd1 = qdot[16 + c];
#pragma unroll
    for (int reg = 0; reg < 4; ++reg) {
      const int r = rbase + reg;
      const float s0 = sdot[r];
      float h0 = acc0[reg] + s0 + qd0;
      float h1 = (c < 14) ? (acc1[reg] + s0 + qd1) : -1e30f;
      float m = fmaxf(h0, h1);
#pragma unroll
      for (int msk = 1; msk < 16; msk <<= 1) m = fmaxf(m, __shfl_xor(m, msk, 64));
      float e0 = expf(h0 - m);
      float e1 = (c < 14) ? expf(h1 - m) : 0.f;
      float ssum = e0 + e1;
#pragma unroll
      for (int msk = 1; msk < 16; msk <<= 1) ssum += __shfl_xor(ssum, msk, 64);
      float inv = 1.f / ssum;
      a_bf[r][c]      = __float2bfloat16(e0 * inv);
      a_bf[r][16 + c] = __float2bfloat16(e1 * inv);
      if (c == 0) hmax[r] = m;
    }
  }
  __syncthreads();

  // ---- phase C: bvec (wave 0), then q2s (two halves of l) ----
  if (w == 0) {
    float v0 = hmax[lane];
    float v1 = (lane < L_ - 64) ? hmax[64 + lane] : -1e30f;
    float m = wred_max64(fmaxf(v0, v1));
    float e0 = expf(v0 - m);
    float e1 = (lane < L_ - 64) ? expf(v1 - m) : 0.f;
    float inv = 1.f / wred_sum64(e0 + e1);
    bvec[lane] = e0 * inv;
    if (lane < L_ - 64) bvec[64 + lane] = e1 * inv;
  }
  __syncthreads();
  if (tid < 2 * D_) {
    const int d = tid % D_, half = tid / D_;
    const bf16* xp = xrow_base + (size_t)(1 + 60 * half) * CPAD_ + d;
    float acc = 0.f;
#pragma unroll 4
    for (int l = 0; l < 60; ++l)
      acc += bvec[60 * half + l] * __bfloat162float(xp[(size_t)l * CPAD_]);
    q2p[half][d] = acc;
  }
  __syncthreads();

  // ---- phase D: GEMM2 + fused x2/x3 writes ----
  {
    const short8 aft = *(const short8*)&a_bf[16 * w + c][g * 8];
    const int rb = 16 * w + 4 * g;
    const f32x4 zz = {0.f, 0.f, 0.f, 0.f};
#pragma unroll
    for (int nt = 0; nt < 13; ++nt) {
      short8 bfr = *(const short8*)&qT[nt * 16 + c][g * 8];
      f32x4 o = __builtin_amdgcn_mfma_f32_16x16x32_bf16(aft, bfr, zz, 0, 0, 0);
      const int d = nt * 16 + c;
      if (d < D_) {
        const float q2 = q2p[0][d] + q2p[1][d];
        bf16* xcol = xrow_base + (size_t)CPAD_ + d;   // row l=0 at offset 1 row
#pragma unroll
        for (int reg = 0; reg < 4; ++reg) {
          const int r = rb + reg;
          if (r < L_) {
            float sval = __bfloat162float(xcol[(size_t)r * CPAD_]);
            xcol[(size_t)r * CPAD_ + D_]     = __float2bfloat16(sval * o[reg]);
            xcol[(size_t)r * CPAD_ + 2 * D_] = __float2bfloat16(sval * q2);
          }
        }
      }
    }
  }
}

// ---------------------------------------------------------------------------
// K2: conv1d(k=3,SAME) as MFMA bf16 GEMM + max-over-time + relu -> feat [N][H]
// grid = N_, block = 512 (8 waves, 2M x 4N). Per-block tile: M=128 pos, N=256 h.
// ---------------------------------------------------------------------------
__global__ __launch_bounds__(512) void k2_conv_mfma(
    const bf16* __restrict__ xbuf, const bf16* __restrict__ wt,
    const float* __restrict__ conv_b, float* __restrict__ feat)
{
  const int n = blockIdx.x;
  const int tid = threadIdx.x;
  const int wave = tid >> 6, lane = tid & 63;
  const int wm = wave >> 2, wn = wave & 3;

  __shared__ short At[130][40];       // rows -1..128 (halo coords), pad-40 stride
  __shared__ float hred[8][64];

  f32x4 acc[4][4];
#pragma unroll
  for (int i = 0; i < 4; ++i)
#pragma unroll
    for (int j = 0; j < 4; ++j) acc[i][j] = (f32x4){0.f, 0.f, 0.f, 0.f};

  const short* xs = (const short*)xbuf;
  const short* wts = (const short*)wt;
  const size_t xbase = (size_t)n * LROWS * CPAD_;
  const int arow = (lane & 15), agrp = (lane >> 4) << 3;

  for (int c0 = 0; c0 < CPAD_; c0 += 32) {
    __syncthreads();
    for (int t = tid; t < 520; t += 512) {
      int r = t >> 2, cc = (t & 3) * 8;
      *(short8*)&At[r][cc] = *(const short8*)(xs + xbase + (size_t)r * CPAD_ + c0 + cc);
    }
    __syncthreads();
#pragma unroll
    for (int k = 0; k < 3; ++k) {
      short8 af[4];
#pragma unroll
      for (int mi = 0; mi < 4; ++mi)
        af[mi] = *(const short8*)&At[wm * 64 + mi * 16 + arow + k][agrp];
#pragma unroll
      for (int ni = 0; ni < 4; ++ni) {
        const short8 bf = *(const short8*)(
            wts + (((size_t)((k * 20 + (c0 >> 5)) * 16 + wn * 4 + ni)) << 9) + lane * 8);
#pragma unroll
        for (int mi = 0; mi < 4; ++mi)
          acc[mi][ni] = __builtin_amdgcn_mfma_f32_16x16x32_bf16(af[mi], bf, acc[mi][ni], 0, 0, 0);
      }
    }
  }

  const int pbase = wm * 64 + ((lane >> 4) << 2);
#pragma unroll
  for (int ni = 0; ni < 4; ++ni) {
    float m = -1e30f;
#pragma unroll
    for (int mi = 0; mi < 4; ++mi) {
#pragma unroll
      for (int reg = 0; reg < 4; ++reg) {
        int pos = pbase + mi * 16 + reg;
        if (pos < L_) m = fmaxf(m, acc[mi][ni][reg]);
      }
    }
    m = fmaxf(m, __shfl_xor(m, 16, 64));
    m = fmaxf(m, __shfl_xor(m, 32, 64));
    if ((lane >> 4) == 0) hred[wave][ni * 16 + (lane & 15)] = m;
  }
  __syncthreads();
  for (int h = tid; h < H_; h += 512) {
    int wn2 = h >> 6, hl = h & 63;
    float m = fmaxf(hred[wn2][hl], hred[wn2 + 4][hl]);
    feat[(size_t)n * H_ + h] = fmaxf(0.f, m + conv_b[h]);
  }
}

// ---------------------------------------------------------------------------
// K3: bag self-attention + selective attention + final projection -> out [B][R]
// ---------------------------------------------------------------------------
__global__ __launch_bounds__(256) void k3_bag(
    const float* __restrict__ feat, const int* __restrict__ X_Rel,
    const float* __restrict__ rel_w, const float* __restrict__ rel_b,
    float* __restrict__ out)
{
  const int b = blockIdx.x;
  const int tid = threadIdx.x;
  __shared__ float f[BAG_][231];
  __shared__ float f2[BAG_][231];
  __shared__ float sc[BAG_][BAG_];
  __shared__ float relq[H_];
  __shared__ float zred[BAG_];
  __shared__ float wsel[BAG_];
  __shared__ float brep[H_];

  for (int t = tid; t < BAG_ * H_; t += 256) {
    int i = t / H_, h = t % H_;
    f[i][h] = feat[(size_t)(b * BAG_ + i) * H_ + h];
  }
  const int rel = X_Rel[b];
  for (int t = tid; t < H_; t += 256) relq[t] = rel_w[(size_t)rel * H_ + t];
  __syncthreads();

  if (tid < BAG_ * BAG_) {
    int i = tid >> 3, j = tid & 7;
    float acc = 0.f;
    for (int h = 0; h < H_; ++h) acc += f[i][h] * f[j][h];
    sc[i][j] = acc * (1.0f / sqrtf((float)H_));
  }
  __syncthreads();
  if (tid < BAG_) {
    float m = -1e30f;
    for (int j = 0; j < BAG_; ++j) m = fmaxf(m, sc[tid][j]);
    float s = 0.f;
    for (int j = 0; j < BAG_; ++j) { float e = expf(sc[tid][j] - m); sc[tid][j] = e; s += e; }
    float inv = 1.0f / s;
    for (int j = 0; j < BAG_; ++j) sc[tid][j] *= inv;
  }
  __syncthreads();
  for (int t = tid; t < BAG_ * H_; t += 256) {
    int i = t / H_, h = t % H_;
    float acc = 0.f;
#pragma unroll
    for (int j = 0; j < BAG_; ++j) acc += sc[i][j] * f[j][h];
    f2[i][h] = acc;
  }
  __syncthreads();
  if (tid < BAG_) {
    float acc = 0.f;
    for (int h = 0; h < H_; ++h) acc += f2[tid][h] * relq[h];
    zred[tid] = acc;
  }
  __syncthreads();
  if (tid == 0) {
    float m = -1e30f;
    for (int i = 0; i < BAG_; ++i) m = fmaxf(m, zred[i]);
    float s = 0.f;
    for (int i = 0; i < BAG_; ++i) { float e = expf(zred[i] - m); wsel[i] = e; s += e; }
    float inv = 1.0f / s;
    for (int i = 0; i < BAG_; ++i) wsel[i] *= inv;
  }
  __syncthreads();
  for (int t = tid; t < H_; t += 256) {
    float acc = 0.f;
#pragma unroll
    for (int i = 0; i < BAG_; ++i) acc += wsel[i] * f2[i][t];
    brep[t] = acc;
  }
  __syncthreads();
  if (tid < R_) {
    float acc = 0.f;
    for (int h = 0; h < H_; ++h) acc += brep[h] * rel_w[(size_t)tid * H_ + h];
    out[(size_t)b * R_ + tid] = acc + rel_b[tid];
  }
}

// ---------------------------------------------------------------------------
extern "C" void kernel_launch(void* const* d_in, const int* in_sizes, int n_in,
                              void* d_out, int out_size, void* d_ws, size_t ws_size,
                              hipStream_t stream)
{
  const int*   X        = (const int*)d_in[0];
  const int*   Q        = (const int*)d_in[1];
  const int*   P1       = (const int*)d_in[2];
  const int*   P2       = (const int*)d_in[3];
  // d_in[4] = X_Scope (uniform bags of 8; bag_id = i/8)
  const int*   X_Rel    = (const int*)d_in[5];
  const float* word_emb = (const float*)d_in[6];
  const float* pos1_emb = (const float*)d_in[7];
  const float* pos2_emb = (const float*)d_in[8];
  const float* ws_w     = (const float*)d_in[9];
  const float* ws_b     = (const float*)d_in[10];
  const float* wq_w     = (const float*)d_in[11];
  const float* wq_b     = (const float*)d_in[12];
  const float* wsq_w    = (const float*)d_in[13];
  const float* wsq_b    = (const float*)d_in[14];
  const float* conv_w   = (const float*)d_in[15];
  const float* conv_b   = (const float*)d_in[16];
  const float* rel_w    = (const float*)d_in[17];
  const float* rel_b    = (const float*)d_in[18];
  (void)wsq_b;  // wsq_b == 0-init scalar; folded: reference adds it to every h
                // (constant shift, softmax-invariant) -- NOTE: actually it IS a
                // constant added to sq; softmax over j is shift-invariant, and
                // hmax shifts cancel in bvec softmax too, so it drops out.

  const size_t xbuf_rows  = (size_t)N_ * LROWS + 8;
  const size_t xbuf_bytes = (xbuf_rows * CPAD_ * sizeof(bf16) + 255) & ~(size_t)255;
  const size_t feat_bytes = ((size_t)N_ * H_ * sizeof(float) + 255) & ~(size_t)255;
  bf16*  xbuf = (bf16*)d_ws;
  float* feat = (float*)((char*)d_ws + xbuf_bytes);
  bf16*  wt   = (bf16*)((char*)d_ws + xbuf_bytes + feat_bytes);

  k0_prep_w<<<1920, 256, 0, stream>>>(conv_w, wt, xbuf);
  k1_attn_build_x<<<N_, 512, 0, stream>>>(X, Q, P1, P2, word_emb, pos1_emb, pos2_emb,
                                          ws_w, ws_b, wq_w, wq_b, wsq_w, wsq_b, xbuf);
  k2_conv_mfma<<<N_, 512, 0, stream>>>(xbuf, wt, conv_b, feat);
  k3_bag<<<B_, 256, 0, stream>>>(feat, X_Rel, rel_w, rel_b, (float*)d_out);
}